// Round 8
// baseline (1953.680 us; speedup 1.0000x reference)
//
#include <hip/hip_runtime.h>
#include <hip/hip_bf16.h>
#include <hip/hip_fp16.h>

#define FDIM 128

typedef float f4 __attribute__((ext_vector_type(4)));

// ---------- degree / dinv ----------

__global__ void degree_kernel(const int* __restrict__ col, int* __restrict__ deg, int E) {
    int e = blockIdx.x * blockDim.x + threadIdx.x;
    if (e < E) atomicAdd(&deg[col[e]], 1);
}

__global__ void dinv_kernel(const int* __restrict__ deg, float* __restrict__ dinv, int N) {
    int i = blockIdx.x * blockDim.x + threadIdx.x;
    if (i < N) {
        int d = deg[i];
        dinv[i] = (d > 0) ? rsqrtf((float)d) : 0.0f;
    }
}

// ---------- exclusive scan of deg -> rowptr ----------

__global__ void scan_blocks_kernel(const int* __restrict__ deg, int* __restrict__ rowptr,
                                   int* __restrict__ bsum, int N) {
    __shared__ int s[256];
    int t = threadIdx.x;
    int i = blockIdx.x * 256 + t;
    int v = (i < N) ? deg[i] : 0;
    s[t] = v;
    __syncthreads();
    for (int off = 1; off < 256; off <<= 1) {
        int add = (t >= off) ? s[t - off] : 0;
        __syncthreads();
        s[t] += add;
        __syncthreads();
    }
    if (i < N) rowptr[i] = s[t] - v;
    if (t == 255) bsum[blockIdx.x] = s[255];
}

__global__ void scan_bsums_kernel(int* __restrict__ bsum, int* __restrict__ boff, int nb) {
    __shared__ int s[512];
    int t = threadIdx.x;
    int v = (t < nb) ? bsum[t] : 0;
    s[t] = v;
    __syncthreads();
    for (int off = 1; off < 512; off <<= 1) {
        int add = (t >= off) ? s[t - off] : 0;
        __syncthreads();
        s[t] += add;
        __syncthreads();
    }
    if (t < nb) boff[t] = s[t] - v;
}

__global__ void add_offsets_kernel(int* __restrict__ rowptr, int* __restrict__ cursor,
                                   const int* __restrict__ boff, int N, int E) {
    int i = blockIdx.x * blockDim.x + threadIdx.x;
    if (i < N) {
        int v = rowptr[i] + boff[i >> 8];
        rowptr[i] = v;
        cursor[i] = v;
    }
    if (i == 0) rowptr[N] = E;
}

// ---------- two-phase octant edge placement ----------
// Phase A: stream edges into 8 dst-octant buffers. Binning ranks are computed
// with wave ballots (8 LDS atomics per WAVE, not 64 per wave: r7's per-thread
// atomicAdd was LDS-serialization-bound, 605K bank conflicts, 148us).
// Phase B: blocks pinned to XCD (bid&7 = octant) scatter into the octant's
// ~3.2MB CSR slice which fits that XCD's L2.

__global__ void octant_init_kernel(const int* __restrict__ rowptr,
                                   int* __restrict__ gcur, int N) {
    int o = threadIdx.x;
    if (o < 8) gcur[o] = rowptr[(int)(((long)o * N + 7) / 8)];
}

__global__ __launch_bounds__(256) void binA_kernel(
        const int* __restrict__ row, const int* __restrict__ col,
        unsigned long long* __restrict__ obuf, int* __restrict__ gcur,
        int N, int E) {
    __shared__ int scnt[8];
    __shared__ int sbase[8];
    __shared__ int wbase[4][8];
    int t = threadIdx.x;
    int wv = t >> 6, lane = t & 63;
    if (t < 8) scnt[t] = 0;
    __syncthreads();
    int e = blockIdx.x * 256 + t;
    bool v = e < E;
    int o = 0;
    unsigned long long pay = 0;
    if (v) {
        int r = row[e], c = col[e];
        o = (int)(((long)c * 8) / N);
        pay = ((unsigned long long)(unsigned)c << 32) | (unsigned)r;
    }
    // wave-ballot binning: no runtime-indexed register arrays (rule #20)
    unsigned long long mymask = 0;
    int mypop = 0;
    #pragma unroll
    for (int q = 0; q < 8; ++q) {
        unsigned long long m = __ballot(v && (o == q));
        if (o == q) mymask = m;
        if (lane == q) mypop = __popcll(m);
    }
    if (lane < 8) wbase[wv][lane] = atomicAdd(&scnt[lane], mypop);
    __syncthreads();
    if (t < 8) sbase[t] = atomicAdd(&gcur[t], scnt[t]);
    __syncthreads();
    if (v) {
        int rank = __popcll(mymask & ((1ull << lane) - 1));
        obuf[sbase[o] + wbase[wv][o] + rank] = pay;
    }
}

__global__ __launch_bounds__(256) void binB_kernel(
        const unsigned long long* __restrict__ obuf, const int* __restrict__ gend,
        const int* __restrict__ rowptr, const float* __restrict__ dinv,
        int* __restrict__ cursor, float2* __restrict__ edata, int N, int M) {
    int o = blockIdx.x & 7;      // octant -> XCD pin
    int j = blockIdx.x >> 3;
    int sb = rowptr[(int)(((long)o * N + 7) / 8)];
    int en = gend[o];
    for (int p = sb + j * 256 + threadIdx.x; p < en; p += M * 256) {
        unsigned long long pay = obuf[p];
        int r = (int)(pay & 0xffffffffu);
        int c = (int)(pay >> 32);
        float w = dinv[r] * dinv[c];
        int pos = atomicAdd(&cursor[c], 1);
        edata[pos] = make_float2(__int_as_float(r), w);
    }
}

// ---------- out = mf[0] * x ; hx = fp16(x), flat layout ----------

__global__ void init_out_kernel(const float4* __restrict__ x, const float* __restrict__ mf,
                                float4* __restrict__ out, float4* __restrict__ hx, long n8) {
    long i = (long)blockIdx.x * blockDim.x + threadIdx.x;
    if (i < n8) {
        float w = mf[0];
        float4 a = x[2 * i];
        float4 b = x[2 * i + 1];
        out[2 * i]     = make_float4(w * a.x, w * a.y, w * a.z, w * a.w);
        out[2 * i + 1] = make_float4(w * b.x, w * b.y, w * b.z, w * b.w);
        __half2 h[4];
        h[0] = __floats2half2_rn(a.x, a.y);
        h[1] = __floats2half2_rn(a.z, a.w);
        h[2] = __floats2half2_rn(b.x, b.y);
        h[3] = __floats2half2_rn(b.z, b.w);
        hx[i] = *(const float4*)h;
    }
}

// ---------- fused gather prop, 4 edges per wave, unroll 8 ----------
// wave = one dst node. lane = 16*g + fl : group g (0..3) processes edge e0+g,
// feature-lane fl (0..15) holds features [8*fl, 8*fl+8). One 1KB gather per
// iteration; unroll 8 -> 32 edges (8KB) in flight per wave. Cross-round data
// (r2 flat 947MB fills vs r6 chunked 275MB, both ~5G gather-instr/s) says the
// gather path is latency/issue-bound, not fill-bound -> MLP is the lever.

__global__ __launch_bounds__(256) void gather_prop_kernel(
        const float2* __restrict__ edata, const int* __restrict__ rowptr,
        const __half* __restrict__ src, const float* __restrict__ prev2,
        float* __restrict__ tgt, __half* __restrict__ tgth, float* __restrict__ out,
        const float* __restrict__ mf, const float* __restrict__ lap,
        int i_coef, float scale, float beta, int N) {
    int wid = blockIdx.x * 4 + (threadIdx.x >> 6);
    if (wid >= N) return;
    int lane = threadIdx.x & 63;
    int g  = lane >> 4;        // edge group within wave
    int fl = lane & 15;        // feature lane
    int feoff = fl << 3;       // element offset within a 128-elem row

    int begin = rowptr[wid];
    int end   = rowptr[wid + 1];

    float acc[8];
    #pragma unroll
    for (int j = 0; j < 8; ++j) acc[j] = 0.f;

    #pragma unroll 8
    for (int e0 = begin; e0 < end; e0 += 4) {
        int e = e0 + g;
        float w = 0.f;
        int idx = 0;
        if (e < end) {
            float2 ed = edata[e];
            idx = __float_as_int(ed.x);
            w = ed.y;
        }
        f4 raw = *(const f4*)(src + ((long)idx << 7) + feoff);
        const __half2* h = (const __half2*)&raw;
        float2 f0 = __half22float2(h[0]);
        float2 f1 = __half22float2(h[1]);
        float2 f2 = __half22float2(h[2]);
        float2 f3 = __half22float2(h[3]);
        acc[0] += w * f0.x; acc[1] += w * f0.y;
        acc[2] += w * f1.x; acc[3] += w * f1.y;
        acc[4] += w * f2.x; acc[5] += w * f2.y;
        acc[6] += w * f3.x; acc[7] += w * f3.y;
    }

    // reduce the 4 edge groups (lanes fl, fl+16, fl+32, fl+48)
    #pragma unroll
    for (int j = 0; j < 8; ++j) {
        acc[j] += __shfl_xor(acc[j], 16, 64);
        acc[j] += __shfl_xor(acc[j], 32, 64);
    }

    if (g == 0) {
        float coef = mf[i_coef] * lap[i_coef - 1];
        long o = ((long)wid << 7) + feoff;   // element offset
        float r[8];
        if (beta != 0.f) {
            f4 p0 = __builtin_nontemporal_load((const f4*)(prev2 + o));
            f4 p1 = __builtin_nontemporal_load((const f4*)(prev2 + o) + 1);
            r[0] = scale * acc[0] + beta * p0.x;
            r[1] = scale * acc[1] + beta * p0.y;
            r[2] = scale * acc[2] + beta * p0.z;
            r[3] = scale * acc[3] + beta * p0.w;
            r[4] = scale * acc[4] + beta * p1.x;
            r[5] = scale * acc[5] + beta * p1.y;
            r[6] = scale * acc[6] + beta * p1.z;
            r[7] = scale * acc[7] + beta * p1.w;
        } else {
            #pragma unroll
            for (int j = 0; j < 8; ++j) r[j] = scale * acc[j];
        }
        f4 t0 = {r[0], r[1], r[2], r[3]};
        f4 t1 = {r[4], r[5], r[6], r[7]};
        __builtin_nontemporal_store(t0, (f4*)(tgt + o));
        __builtin_nontemporal_store(t1, (f4*)(tgt + o) + 1);
        if (tgth) {
            __half2 hh[4];
            hh[0] = __floats2half2_rn(r[0], r[1]);
            hh[1] = __floats2half2_rn(r[2], r[3]);
            hh[2] = __floats2half2_rn(r[4], r[5]);
            hh[3] = __floats2half2_rn(r[6], r[7]);
            __builtin_nontemporal_store(*(const f4*)hh, (f4*)(tgth + o));
        }
        f4 o0 = __builtin_nontemporal_load((const f4*)(out + o));
        f4 o1 = __builtin_nontemporal_load((const f4*)(out + o) + 1);
        o0.x += coef * r[0]; o0.y += coef * r[1]; o0.z += coef * r[2]; o0.w += coef * r[3];
        o1.x += coef * r[4]; o1.y += coef * r[5]; o1.z += coef * r[6]; o1.w += coef * r[7];
        __builtin_nontemporal_store(o0, (f4*)(out + o));
        __builtin_nontemporal_store(o1, (f4*)(out + o) + 1);
    }
}

extern "C" void kernel_launch(void* const* d_in, const int* in_sizes, int n_in,
                              void* d_out, int out_size, void* d_ws, size_t ws_size,
                              hipStream_t stream) {
    const float* x   = (const float*)d_in[0];
    const float* mf  = (const float*)d_in[1];
    const float* lap = (const float*)d_in[2];
    const int*   ei  = (const int*)d_in[3];
    float* out = (float*)d_out;

    const int  K  = in_sizes[1] - 1;          // 10
    const long NF = (long)in_sizes[0];        // N*F
    const int  N  = (int)(NF / FDIM);         // 100000
    const int  E  = in_sizes[3] / 2;          // 3200000
    const int* row = ei;
    const int* col = ei + E;

    // workspace layout (~180 MB)
    char* wp = (char*)d_ws;
    float*  bufA   = (float*)wp;  wp += NF * sizeof(float);
    float*  bufB   = (float*)wp;  wp += NF * sizeof(float);
    __half* hbufA  = (__half*)wp; wp += NF * sizeof(__half);
    __half* hbufB  = (__half*)wp; wp += NF * sizeof(__half);
    float2* edata  = (float2*)wp; wp += (size_t)E * sizeof(float2);
    int*    rowptr = (int*)wp;    wp += (size_t)(N + 1) * sizeof(int);
    int*    cursor = (int*)wp;    wp += (size_t)N * sizeof(int);
    int*    deg    = (int*)wp;    wp += (size_t)N * sizeof(int);
    float*  dinv   = (float*)wp;  wp += (size_t)N * sizeof(float);
    int*    bsum   = (int*)wp;    wp += 512 * sizeof(int);
    int*    boff   = (int*)wp;    wp += 512 * sizeof(int);
    int*    gcur   = (int*)wp;    wp += 8 * sizeof(int);

    // octant append buffer aliases bufA (only written by gathers, which run later)
    unsigned long long* obuf = (unsigned long long*)bufA;

    const int BT = 256;
    const long n8 = NF / 8;
    const int n8_blocks = (int)((n8 + BT - 1) / BT);
    const int e_blocks  = (E + BT - 1) / BT;
    const int n_blocks  = (N + BT - 1) / BT;

    // CSR build
    hipMemsetAsync(deg, 0, (size_t)N * sizeof(int), stream);
    degree_kernel<<<e_blocks, BT, 0, stream>>>(col, deg, E);
    dinv_kernel<<<n_blocks, BT, 0, stream>>>(deg, dinv, N);
    scan_blocks_kernel<<<n_blocks, BT, 0, stream>>>(deg, rowptr, bsum, N);
    scan_bsums_kernel<<<1, 512, 0, stream>>>(bsum, boff, n_blocks);
    add_offsets_kernel<<<n_blocks, BT, 0, stream>>>(rowptr, cursor, boff, N, E);
    octant_init_kernel<<<1, 8, 0, stream>>>(rowptr, gcur, N);
    binA_kernel<<<e_blocks, BT, 0, stream>>>(row, col, obuf, gcur, N, E);
    const int M = 256;   // blocks per octant in phase B
    binB_kernel<<<8 * M, BT, 0, stream>>>(obuf, gcur, rowptr, dinv, cursor, edata, N, M);

    // out = mf0 * x ; hbufB = fp16(x) flat  (hbufB free until i=2 writes it)
    init_out_kernel<<<n8_blocks, BT, 0, stream>>>((const float4*)x, mf, (float4*)out,
                                                  (float4*)hbufB, n8);

    const int g_blocks = (N + 3) / 4;

    // P1 = prop(x) -> bufA (+hbufA) ; out += c1*P1   (gathers fp16 copy of x)
    gather_prop_kernel<<<g_blocks, BT, 0, stream>>>(edata, rowptr, hbufB, x,
                                                    bufA, hbufA, out, mf, lap,
                                                    1, 1.0f, 0.0f, N);
    // P_i = 2*prop(P_{i-1}) - P_{i-2} ; out += c_i*P_i   (gathers fp16 shadow)
    for (int i = 2; i <= K; ++i) {
        const __half* srch  = (i % 2 == 0) ? hbufA : hbufB;  // fp16(P_{i-1})
        float*        tgt   = (i % 2 == 0) ? bufB : bufA;    // P_i (overwrites P_{i-2})
        __half*       tgth  = (i % 2 == 0) ? hbufB : hbufA;
        const float*  prev2 = (i == 2) ? x : (const float*)tgt;
        if (i == K) tgth = nullptr;  // last shadow never gathered
        gather_prop_kernel<<<g_blocks, BT, 0, stream>>>(edata, rowptr, srch, prev2,
                                                        tgt, tgth, out, mf, lap,
                                                        i, 2.0f, -1.0f, N);
    }
}

// Round 9
// 1875.042 us; speedup vs baseline: 1.0419x; 1.0419x over previous
//
#include <hip/hip_runtime.h>
#include <hip/hip_bf16.h>
#include <hip/hip_fp16.h>

#define FDIM 128

typedef float f4 __attribute__((ext_vector_type(4)));

// ---------- degree / dinv ----------

__global__ void degree_kernel(const int* __restrict__ col, int* __restrict__ deg, int E) {
    int e = blockIdx.x * blockDim.x + threadIdx.x;
    if (e < E) atomicAdd(&deg[col[e]], 1);
}

__global__ void dinv_kernel(const int* __restrict__ deg, float* __restrict__ dinv, int N) {
    int i = blockIdx.x * blockDim.x + threadIdx.x;
    if (i < N) {
        int d = deg[i];
        dinv[i] = (d > 0) ? rsqrtf((float)d) : 0.0f;
    }
}

// ---------- exclusive scan of deg -> rowptr ----------

__global__ void scan_blocks_kernel(const int* __restrict__ deg, int* __restrict__ rowptr,
                                   int* __restrict__ bsum, int N) {
    __shared__ int s[256];
    int t = threadIdx.x;
    int i = blockIdx.x * 256 + t;
    int v = (i < N) ? deg[i] : 0;
    s[t] = v;
    __syncthreads();
    for (int off = 1; off < 256; off <<= 1) {
        int add = (t >= off) ? s[t - off] : 0;
        __syncthreads();
        s[t] += add;
        __syncthreads();
    }
    if (i < N) rowptr[i] = s[t] - v;
    if (t == 255) bsum[blockIdx.x] = s[255];
}

__global__ void scan_bsums_kernel(int* __restrict__ bsum, int* __restrict__ boff, int nb) {
    __shared__ int s[512];
    int t = threadIdx.x;
    int v = (t < nb) ? bsum[t] : 0;
    s[t] = v;
    __syncthreads();
    for (int off = 1; off < 512; off <<= 1) {
        int add = (t >= off) ? s[t - off] : 0;
        __syncthreads();
        s[t] += add;
        __syncthreads();
    }
    if (t < nb) boff[t] = s[t] - v;
}

__global__ void add_offsets_kernel(int* __restrict__ rowptr, int* __restrict__ cursor,
                                   const int* __restrict__ boff, int N, int E) {
    int i = blockIdx.x * blockDim.x + threadIdx.x;
    if (i < N) {
        int v = rowptr[i] + boff[i >> 8];
        rowptr[i] = v;
        cursor[i] = v;
    }
    if (i == 0) rowptr[N] = E;
}

// ---------- edge placement: CSR by destination, 4B index only ----------
// dinv[r] is folded into the fp16 shadow rows and dinv[c] applied in the
// gather epilogue (r3-verified math), so the scatter payload is just the src
// index: 12.8MB target instead of 25.6MB -> roughly half the dirty-line
// write amplification that made r2's place 170us / 200MB WRITE.

__global__ void place_kernel(const int* __restrict__ row, const int* __restrict__ col,
                             int* __restrict__ cursor, int* __restrict__ eidx, int E) {
    int e = blockIdx.x * blockDim.x + threadIdx.x;
    if (e < E) {
        int c = col[e];
        int pos = atomicAdd(&cursor[c], 1);
        eidx[pos] = row[e];
    }
}

// ---------- out = mf[0] * x ; hx = fp16(dinv[n] * x), flat layout ----------

__global__ void init_out_kernel(const float4* __restrict__ x, const float* __restrict__ mf,
                                const float* __restrict__ dinv,
                                float4* __restrict__ out, float4* __restrict__ hx, long n8) {
    long i = (long)blockIdx.x * blockDim.x + threadIdx.x;
    if (i < n8) {
        float w = mf[0];
        float4 a = x[2 * i];
        float4 b = x[2 * i + 1];
        out[2 * i]     = make_float4(w * a.x, w * a.y, w * a.z, w * a.w);
        out[2 * i + 1] = make_float4(w * b.x, w * b.y, w * b.z, w * b.w);
        float dv = dinv[i >> 4];     // node = i/16 (16 threads per 128-f row)
        __half2 h[4];
        h[0] = __floats2half2_rn(dv * a.x, dv * a.y);
        h[1] = __floats2half2_rn(dv * a.z, dv * a.w);
        h[2] = __floats2half2_rn(dv * b.x, dv * b.y);
        h[3] = __floats2half2_rn(dv * b.z, dv * b.w);
        hx[i] = *(const float4*)h;
    }
}

// ---------- fused gather prop, 4 edges per wave (r2-proven shape) ----------
// wave = one dst node. lane = 16*g + fl : group g (0..3) processes edge e0+g,
// feature-lane fl (0..15) holds features [8*fl, 8*fl+8). One 1KB gather per
// iteration (4 x 256B fully-utilized rows). This dispatch runs at the ~6.4TB/s
// L2-fill/fabric ceiling (r8 audit: ~950MB L2-miss traffic / 148us; unroll
// 4->8 changed nothing) -> only stream-byte reduction helps from here.
// Shadow carries dinv[r] (r3 math):
//   P_i(d) = scale * dinv[d] * sum_e shadow_{i-1}[r_e] + beta * P_{i-2}(d)
//   shadow_i(d) = fp16(dinv[d] * P_i(d)) ; out += coef * P_i(d)

__global__ __launch_bounds__(256) void gather_prop_kernel(
        const int* __restrict__ eidx, const int* __restrict__ rowptr,
        const float* __restrict__ dinv,
        const __half* __restrict__ src, const float* __restrict__ prev2,
        float* __restrict__ tgt, __half* __restrict__ tgth, float* __restrict__ out,
        const float* __restrict__ mf, const float* __restrict__ lap,
        int i_coef, float scale, float beta, int N) {
    int wid = blockIdx.x * 4 + (threadIdx.x >> 6);
    if (wid >= N) return;
    int lane = threadIdx.x & 63;
    int g  = lane >> 4;        // edge group within wave
    int fl = lane & 15;        // feature lane
    int feoff = fl << 3;       // element offset within a 128-elem row

    int begin = rowptr[wid];
    int end   = rowptr[wid + 1];

    float acc[8];
    #pragma unroll
    for (int j = 0; j < 8; ++j) acc[j] = 0.f;

    #pragma unroll 4
    for (int e0 = begin; e0 < end; e0 += 4) {
        int e = e0 + g;
        float wsel = 0.f;
        int idx = 0;
        if (e < end) {
            idx = eidx[e];
            wsel = 1.f;
        }
        f4 raw = *(const f4*)(src + ((long)idx << 7) + feoff);
        const __half2* h = (const __half2*)&raw;
        float2 f0 = __half22float2(h[0]);
        float2 f1 = __half22float2(h[1]);
        float2 f2 = __half22float2(h[2]);
        float2 f3 = __half22float2(h[3]);
        acc[0] += wsel * f0.x; acc[1] += wsel * f0.y;
        acc[2] += wsel * f1.x; acc[3] += wsel * f1.y;
        acc[4] += wsel * f2.x; acc[5] += wsel * f2.y;
        acc[6] += wsel * f3.x; acc[7] += wsel * f3.y;
    }

    // reduce the 4 edge groups (lanes fl, fl+16, fl+32, fl+48)
    #pragma unroll
    for (int j = 0; j < 8; ++j) {
        acc[j] += __shfl_xor(acc[j], 16, 64);
        acc[j] += __shfl_xor(acc[j], 32, 64);
    }

    if (g == 0) {
        float dv   = dinv[wid];
        float sdv  = scale * dv;
        float coef = mf[i_coef] * lap[i_coef - 1];
        long o = ((long)wid << 7) + feoff;   // element offset
        float r[8];
        if (beta != 0.f) {
            f4 p0 = __builtin_nontemporal_load((const f4*)(prev2 + o));
            f4 p1 = __builtin_nontemporal_load((const f4*)(prev2 + o) + 1);
            r[0] = sdv * acc[0] + beta * p0.x;
            r[1] = sdv * acc[1] + beta * p0.y;
            r[2] = sdv * acc[2] + beta * p0.z;
            r[3] = sdv * acc[3] + beta * p0.w;
            r[4] = sdv * acc[4] + beta * p1.x;
            r[5] = sdv * acc[5] + beta * p1.y;
            r[6] = sdv * acc[6] + beta * p1.z;
            r[7] = sdv * acc[7] + beta * p1.w;
        } else {
            #pragma unroll
            for (int j = 0; j < 8; ++j) r[j] = sdv * acc[j];
        }
        f4 t0 = {r[0], r[1], r[2], r[3]};
        f4 t1 = {r[4], r[5], r[6], r[7]};
        __builtin_nontemporal_store(t0, (f4*)(tgt + o));
        __builtin_nontemporal_store(t1, (f4*)(tgt + o) + 1);
        if (tgth) {
            __half2 hh[4];
            hh[0] = __floats2half2_rn(dv * r[0], dv * r[1]);
            hh[1] = __floats2half2_rn(dv * r[2], dv * r[3]);
            hh[2] = __floats2half2_rn(dv * r[4], dv * r[5]);
            hh[3] = __floats2half2_rn(dv * r[6], dv * r[7]);
            __builtin_nontemporal_store(*(const f4*)hh, (f4*)(tgth + o));
        }
        f4 o0 = __builtin_nontemporal_load((const f4*)(out + o));
        f4 o1 = __builtin_nontemporal_load((const f4*)(out + o) + 1);
        o0.x += coef * r[0]; o0.y += coef * r[1]; o0.z += coef * r[2]; o0.w += coef * r[3];
        o1.x += coef * r[4]; o1.y += coef * r[5]; o1.z += coef * r[6]; o1.w += coef * r[7];
        __builtin_nontemporal_store(o0, (f4*)(out + o));
        __builtin_nontemporal_store(o1, (f4*)(out + o) + 1);
    }
}

extern "C" void kernel_launch(void* const* d_in, const int* in_sizes, int n_in,
                              void* d_out, int out_size, void* d_ws, size_t ws_size,
                              hipStream_t stream) {
    const float* x   = (const float*)d_in[0];
    const float* mf  = (const float*)d_in[1];
    const float* lap = (const float*)d_in[2];
    const int*   ei  = (const int*)d_in[3];
    float* out = (float*)d_out;

    const int  K  = in_sizes[1] - 1;          // 10
    const long NF = (long)in_sizes[0];        // N*F
    const int  N  = (int)(NF / FDIM);         // 100000
    const int  E  = in_sizes[3] / 2;          // 3200000
    const int* row = ei;
    const int* col = ei + E;

    // workspace layout (~170 MB)
    char* wp = (char*)d_ws;
    float*  bufA   = (float*)wp;  wp += NF * sizeof(float);
    float*  bufB   = (float*)wp;  wp += NF * sizeof(float);
    __half* hbufA  = (__half*)wp; wp += NF * sizeof(__half);
    __half* hbufB  = (__half*)wp; wp += NF * sizeof(__half);
    int*    eidx   = (int*)wp;    wp += (size_t)E * sizeof(int);
    int*    rowptr = (int*)wp;    wp += (size_t)(N + 1) * sizeof(int);
    int*    cursor = (int*)wp;    wp += (size_t)N * sizeof(int);
    int*    deg    = (int*)wp;    wp += (size_t)N * sizeof(int);
    float*  dinv   = (float*)wp;  wp += (size_t)N * sizeof(float);
    int*    bsum   = (int*)wp;    wp += 512 * sizeof(int);
    int*    boff   = (int*)wp;    wp += 512 * sizeof(int);

    const int BT = 256;
    const long n8 = NF / 8;
    const int n8_blocks = (int)((n8 + BT - 1) / BT);
    const int e_blocks  = (E + BT - 1) / BT;
    const int n_blocks  = (N + BT - 1) / BT;

    // CSR build
    hipMemsetAsync(deg, 0, (size_t)N * sizeof(int), stream);
    degree_kernel<<<e_blocks, BT, 0, stream>>>(col, deg, E);
    dinv_kernel<<<n_blocks, BT, 0, stream>>>(deg, dinv, N);
    scan_blocks_kernel<<<n_blocks, BT, 0, stream>>>(deg, rowptr, bsum, N);
    scan_bsums_kernel<<<1, 512, 0, stream>>>(bsum, boff, n_blocks);
    add_offsets_kernel<<<n_blocks, BT, 0, stream>>>(rowptr, cursor, boff, N, E);
    place_kernel<<<e_blocks, BT, 0, stream>>>(row, col, cursor, eidx, E);

    // out = mf0 * x ; hbufB = fp16(dinv*x) flat  (hbufB free until i=2 writes it)
    init_out_kernel<<<n8_blocks, BT, 0, stream>>>((const float4*)x, mf, dinv,
                                                  (float4*)out, (float4*)hbufB, n8);

    const int g_blocks = (N + 3) / 4;

    // P1 = prop(x) -> bufA (+hbufA) ; out += c1*P1   (gathers fp16 dinv*x)
    gather_prop_kernel<<<g_blocks, BT, 0, stream>>>(eidx, rowptr, dinv, hbufB, x,
                                                    bufA, hbufA, out, mf, lap,
                                                    1, 1.0f, 0.0f, N);
    // P_i = 2*prop(P_{i-1}) - P_{i-2} ; out += c_i*P_i   (gathers fp16 shadow)
    for (int i = 2; i <= K; ++i) {
        const __half* srch  = (i % 2 == 0) ? hbufA : hbufB;  // fp16(dinv*P_{i-1})
        float*        tgt   = (i % 2 == 0) ? bufB : bufA;    // P_i (overwrites P_{i-2})
        __half*       tgth  = (i % 2 == 0) ? hbufB : hbufA;
        const float*  prev2 = (i == 2) ? x : (const float*)tgt;
        if (i == K) tgth = nullptr;  // last shadow never gathered
        gather_prop_kernel<<<g_blocks, BT, 0, stream>>>(eidx, rowptr, dinv, srch, prev2,
                                                        tgt, tgth, out, mf, lap,
                                                        i, 2.0f, -1.0f, N);
    }
}

// Round 10
// 1753.091 us; speedup vs baseline: 1.1144x; 1.0696x over previous
//
#include <hip/hip_runtime.h>
#include <hip/hip_bf16.h>
#include <hip/hip_fp16.h>

#define FDIM 128

typedef float f4 __attribute__((ext_vector_type(4)));

// ---------- degree / dinv : XCD-filtered ----------
// Each octant-group (bid&7 -> XCD, r3/r6-verified pinning) streams ALL of col
// (sequential, L3-served) and atomics only its own 50KB deg slice -> atomics
// are L2-local instead of cross-die scattered.

__global__ __launch_bounds__(256) void degree_oct_kernel(
        const int* __restrict__ col, int* __restrict__ deg, int N, int E, int M) {
    int o = blockIdx.x & 7;
    int j = blockIdx.x >> 3;
    int lo = (int)(((long)o * N) >> 3);
    int hi = (int)(((long)(o + 1) * N) >> 3);
    for (int e = j * 256 + threadIdx.x; e < E; e += M * 256) {
        int c = col[e];
        if (c >= lo && c < hi) atomicAdd(&deg[c], 1);
    }
}

__global__ void dinv_kernel(const int* __restrict__ deg, float* __restrict__ dinv, int N) {
    int i = blockIdx.x * blockDim.x + threadIdx.x;
    if (i < N) {
        int d = deg[i];
        dinv[i] = (d > 0) ? rsqrtf((float)d) : 0.0f;
    }
}

// ---------- exclusive scan of deg -> rowptr ----------

__global__ void scan_blocks_kernel(const int* __restrict__ deg, int* __restrict__ rowptr,
                                   int* __restrict__ bsum, int N) {
    __shared__ int s[256];
    int t = threadIdx.x;
    int i = blockIdx.x * 256 + t;
    int v = (i < N) ? deg[i] : 0;
    s[t] = v;
    __syncthreads();
    for (int off = 1; off < 256; off <<= 1) {
        int add = (t >= off) ? s[t - off] : 0;
        __syncthreads();
        s[t] += add;
        __syncthreads();
    }
    if (i < N) rowptr[i] = s[t] - v;
    if (t == 255) bsum[blockIdx.x] = s[255];
}

__global__ void scan_bsums_kernel(int* __restrict__ bsum, int* __restrict__ boff, int nb) {
    __shared__ int s[512];
    int t = threadIdx.x;
    int v = (t < nb) ? bsum[t] : 0;
    s[t] = v;
    __syncthreads();
    for (int off = 1; off < 512; off <<= 1) {
        int add = (t >= off) ? s[t - off] : 0;
        __syncthreads();
        s[t] += add;
        __syncthreads();
    }
    if (t < nb) boff[t] = s[t] - v;
}

__global__ void add_offsets_kernel(int* __restrict__ rowptr, int* __restrict__ cursor,
                                   const int* __restrict__ boff, int N, int E) {
    int i = blockIdx.x * blockDim.x + threadIdx.x;
    if (i < N) {
        int v = rowptr[i] + boff[i >> 8];
        rowptr[i] = v;
        cursor[i] = v;
    }
    if (i == 0) rowptr[N] = E;
}

// ---------- edge placement: XCD-filtered replicated-read scatter ----------
// r9 post-mortem: scatter cost is per-edge LINE eviction (3.2M x 64B = 195MB
// WRITE regardless of payload). Fix locality, not bytes: octant-group o only
// places edges with dst in its node slice -> cursor slice (50KB) and eidx
// slice (1.6MB) are L2-resident on that XCD; lines accumulate all sharers
// before writeback. Reads are replicated 8x (205MB, sequential, L3-served).

__global__ __launch_bounds__(256) void place_oct_kernel(
        const int* __restrict__ row, const int* __restrict__ col,
        int* __restrict__ cursor, int* __restrict__ eidx, int N, int E, int M) {
    int o = blockIdx.x & 7;
    int j = blockIdx.x >> 3;
    int lo = (int)(((long)o * N) >> 3);
    int hi = (int)(((long)(o + 1) * N) >> 3);
    for (int e = j * 256 + threadIdx.x; e < E; e += M * 256) {
        int c = col[e];
        if (c >= lo && c < hi) {
            int pos = atomicAdd(&cursor[c], 1);
            eidx[pos] = row[e];
        }
    }
}

// ---------- out = mf[0] * x ; hx = fp16(dinv[n] * x), flat layout ----------

__global__ void init_out_kernel(const float4* __restrict__ x, const float* __restrict__ mf,
                                const float* __restrict__ dinv,
                                float4* __restrict__ out, float4* __restrict__ hx, long n8) {
    long i = (long)blockIdx.x * blockDim.x + threadIdx.x;
    if (i < n8) {
        float w = mf[0];
        float4 a = x[2 * i];
        float4 b = x[2 * i + 1];
        out[2 * i]     = make_float4(w * a.x, w * a.y, w * a.z, w * a.w);
        out[2 * i + 1] = make_float4(w * b.x, w * b.y, w * b.z, w * b.w);
        float dv = dinv[i >> 4];     // node = i/16 (16 threads per 128-f row)
        __half2 h[4];
        h[0] = __floats2half2_rn(dv * a.x, dv * a.y);
        h[1] = __floats2half2_rn(dv * a.z, dv * a.w);
        h[2] = __floats2half2_rn(dv * b.x, dv * b.y);
        h[3] = __floats2half2_rn(dv * b.z, dv * b.w);
        hx[i] = *(const float4*)h;
    }
}

// ---------- fused gather prop, 4 edges per wave (r2-proven shape) ----------
// At the ~6.4TB/s L2-fill/fabric roofline (r8 audit; unroll 4->8 null) —
// do not touch. Shadow carries dinv[r] (r3 math):
//   P_i(d) = scale * dinv[d] * sum_e shadow_{i-1}[r_e] + beta * P_{i-2}(d)
//   shadow_i(d) = fp16(dinv[d] * P_i(d)) ; out += coef * P_i(d)

__global__ __launch_bounds__(256) void gather_prop_kernel(
        const int* __restrict__ eidx, const int* __restrict__ rowptr,
        const float* __restrict__ dinv,
        const __half* __restrict__ src, const float* __restrict__ prev2,
        float* __restrict__ tgt, __half* __restrict__ tgth, float* __restrict__ out,
        const float* __restrict__ mf, const float* __restrict__ lap,
        int i_coef, float scale, float beta, int N) {
    int wid = blockIdx.x * 4 + (threadIdx.x >> 6);
    if (wid >= N) return;
    int lane = threadIdx.x & 63;
    int g  = lane >> 4;        // edge group within wave
    int fl = lane & 15;        // feature lane
    int feoff = fl << 3;       // element offset within a 128-elem row

    int begin = rowptr[wid];
    int end   = rowptr[wid + 1];

    float acc[8];
    #pragma unroll
    for (int j = 0; j < 8; ++j) acc[j] = 0.f;

    #pragma unroll 4
    for (int e0 = begin; e0 < end; e0 += 4) {
        int e = e0 + g;
        float wsel = 0.f;
        int idx = 0;
        if (e < end) {
            idx = eidx[e];
            wsel = 1.f;
        }
        f4 raw = *(const f4*)(src + ((long)idx << 7) + feoff);
        const __half2* h = (const __half2*)&raw;
        float2 f0 = __half22float2(h[0]);
        float2 f1 = __half22float2(h[1]);
        float2 f2 = __half22float2(h[2]);
        float2 f3 = __half22float2(h[3]);
        acc[0] += wsel * f0.x; acc[1] += wsel * f0.y;
        acc[2] += wsel * f1.x; acc[3] += wsel * f1.y;
        acc[4] += wsel * f2.x; acc[5] += wsel * f2.y;
        acc[6] += wsel * f3.x; acc[7] += wsel * f3.y;
    }

    // reduce the 4 edge groups (lanes fl, fl+16, fl+32, fl+48)
    #pragma unroll
    for (int j = 0; j < 8; ++j) {
        acc[j] += __shfl_xor(acc[j], 16, 64);
        acc[j] += __shfl_xor(acc[j], 32, 64);
    }

    if (g == 0) {
        float dv   = dinv[wid];
        float sdv  = scale * dv;
        float coef = mf[i_coef] * lap[i_coef - 1];
        long o = ((long)wid << 7) + feoff;   // element offset
        float r[8];
        if (beta != 0.f) {
            f4 p0 = __builtin_nontemporal_load((const f4*)(prev2 + o));
            f4 p1 = __builtin_nontemporal_load((const f4*)(prev2 + o) + 1);
            r[0] = sdv * acc[0] + beta * p0.x;
            r[1] = sdv * acc[1] + beta * p0.y;
            r[2] = sdv * acc[2] + beta * p0.z;
            r[3] = sdv * acc[3] + beta * p0.w;
            r[4] = sdv * acc[4] + beta * p1.x;
            r[5] = sdv * acc[5] + beta * p1.y;
            r[6] = sdv * acc[6] + beta * p1.z;
            r[7] = sdv * acc[7] + beta * p1.w;
        } else {
            #pragma unroll
            for (int j = 0; j < 8; ++j) r[j] = sdv * acc[j];
        }
        f4 t0 = {r[0], r[1], r[2], r[3]};
        f4 t1 = {r[4], r[5], r[6], r[7]};
        __builtin_nontemporal_store(t0, (f4*)(tgt + o));
        __builtin_nontemporal_store(t1, (f4*)(tgt + o) + 1);
        if (tgth) {
            __half2 hh[4];
            hh[0] = __floats2half2_rn(dv * r[0], dv * r[1]);
            hh[1] = __floats2half2_rn(dv * r[2], dv * r[3]);
            hh[2] = __floats2half2_rn(dv * r[4], dv * r[5]);
            hh[3] = __floats2half2_rn(dv * r[6], dv * r[7]);
            __builtin_nontemporal_store(*(const f4*)hh, (f4*)(tgth + o));
        }
        f4 o0 = __builtin_nontemporal_load((const f4*)(out + o));
        f4 o1 = __builtin_nontemporal_load((const f4*)(out + o) + 1);
        o0.x += coef * r[0]; o0.y += coef * r[1]; o0.z += coef * r[2]; o0.w += coef * r[3];
        o1.x += coef * r[4]; o1.y += coef * r[5]; o1.z += coef * r[6]; o1.w += coef * r[7];
        __builtin_nontemporal_store(o0, (f4*)(out + o));
        __builtin_nontemporal_store(o1, (f4*)(out + o) + 1);
    }
}

extern "C" void kernel_launch(void* const* d_in, const int* in_sizes, int n_in,
                              void* d_out, int out_size, void* d_ws, size_t ws_size,
                              hipStream_t stream) {
    const float* x   = (const float*)d_in[0];
    const float* mf  = (const float*)d_in[1];
    const float* lap = (const float*)d_in[2];
    const int*   ei  = (const int*)d_in[3];
    float* out = (float*)d_out;

    const int  K  = in_sizes[1] - 1;          // 10
    const long NF = (long)in_sizes[0];        // N*F
    const int  N  = (int)(NF / FDIM);         // 100000
    const int  E  = in_sizes[3] / 2;          // 3200000
    const int* row = ei;
    const int* col = ei + E;

    // workspace layout (~170 MB)
    char* wp = (char*)d_ws;
    float*  bufA   = (float*)wp;  wp += NF * sizeof(float);
    float*  bufB   = (float*)wp;  wp += NF * sizeof(float);
    __half* hbufA  = (__half*)wp; wp += NF * sizeof(__half);
    __half* hbufB  = (__half*)wp; wp += NF * sizeof(__half);
    int*    eidx   = (int*)wp;    wp += (size_t)E * sizeof(int);
    int*    rowptr = (int*)wp;    wp += (size_t)(N + 1) * sizeof(int);
    int*    cursor = (int*)wp;    wp += (size_t)N * sizeof(int);
    int*    deg    = (int*)wp;    wp += (size_t)N * sizeof(int);
    float*  dinv   = (float*)wp;  wp += (size_t)N * sizeof(float);
    int*    bsum   = (int*)wp;    wp += 512 * sizeof(int);
    int*    boff   = (int*)wp;    wp += 512 * sizeof(int);

    const int BT = 256;
    const long n8 = NF / 8;
    const int n8_blocks = (int)((n8 + BT - 1) / BT);
    const int n_blocks  = (N + BT - 1) / BT;
    const int M = 192;   // blocks per octant for filtered kernels

    // CSR build
    hipMemsetAsync(deg, 0, (size_t)N * sizeof(int), stream);
    degree_oct_kernel<<<8 * M, BT, 0, stream>>>(col, deg, N, E, M);
    dinv_kernel<<<n_blocks, BT, 0, stream>>>(deg, dinv, N);
    scan_blocks_kernel<<<n_blocks, BT, 0, stream>>>(deg, rowptr, bsum, N);
    scan_bsums_kernel<<<1, 512, 0, stream>>>(bsum, boff, n_blocks);
    add_offsets_kernel<<<n_blocks, BT, 0, stream>>>(rowptr, cursor, boff, N, E);
    place_oct_kernel<<<8 * M, BT, 0, stream>>>(row, col, cursor, eidx, N, E, M);

    // out = mf0 * x ; hbufB = fp16(dinv*x) flat  (hbufB free until i=2 writes it)
    init_out_kernel<<<n8_blocks, BT, 0, stream>>>((const float4*)x, mf, dinv,
                                                  (float4*)out, (float4*)hbufB, n8);

    const int g_blocks = (N + 3) / 4;

    // P1 = prop(x) -> bufA (+hbufA) ; out += c1*P1   (gathers fp16 dinv*x)
    gather_prop_kernel<<<g_blocks, BT, 0, stream>>>(eidx, rowptr, dinv, hbufB, x,
                                                    bufA, hbufA, out, mf, lap,
                                                    1, 1.0f, 0.0f, N);
    // P_i = 2*prop(P_{i-1}) - P_{i-2} ; out += c_i*P_i   (gathers fp16 shadow)
    for (int i = 2; i <= K; ++i) {
        const __half* srch  = (i % 2 == 0) ? hbufA : hbufB;  // fp16(dinv*P_{i-1})
        float*        tgt   = (i % 2 == 0) ? bufB : bufA;    // P_i (overwrites P_{i-2})
        __half*       tgth  = (i % 2 == 0) ? hbufB : hbufA;
        const float*  prev2 = (i == 2) ? x : (const float*)tgt;
        if (i == K) tgth = nullptr;  // last shadow never gathered
        gather_prop_kernel<<<g_blocks, BT, 0, stream>>>(eidx, rowptr, dinv, srch, prev2,
                                                        tgt, tgth, out, mf, lap,
                                                        i, 2.0f, -1.0f, N);
    }
}